// Round 7
// baseline (259.019 us; speedup 1.0000x reference)
//
#include <hip/hip_runtime.h>
#include <math.h>

// ---------------- problem constants (from setup_inputs) ----------------
// B=64, n_mel=80, T_mel=1000, N_dec=1000, T_enc=250, n_spk=128, n_aug=10, z=16
constexpr int NMEL  = 64 * 80 * 1000;   // 5,120,000 elems per mel tensor
constexpr int NAL   = 64 * 1000 * 250;  // 16,000,000 alignment elems
constexpr int NGATE = 64 * 1000;        // 64,000
constexpr int NKL   = 64 * 16;          // 1024
constexpr int NMEL4 = NMEL / 4;         // 1,280,000 float4
constexpr int NAL4  = NAL / 4;          // 4,000,000 float4

// ---------------- block-role partition: EXACTLY 8 WG/CU ----------------
// 2048 WGs total = 256 CU x 8 (32 waves/CU = HW max residency).
//   bid % 4 == 0 -> mel (512), else align (1530) + tail gate(4)/KL(1)/CE(1)
#define NB_MEL   512
#define NB_AL    1530
#define NB_GATE  4
#define NBLOCKS  2048

// ws layout (doubles), one slot per block partial -> NO atomics for sums:
#define WS_MEL   0         // 512 (s1+s2 combined)
#define WS_AL    512       // 1530
#define WS_GATE  2042      // 4
#define WS_KL    2046
#define WS_SPK   2047
#define WS_AUG   2048
// done-counter (uint) at double-slot 2050 (byte offset 16400)
#define WS_CNT_OFF_BYTES  16400

__device__ inline float wave_red_sum(float v) {
#pragma unroll
    for (int o = 32; o; o >>= 1) v += __shfl_down(v, o, 64);
    return v;
}

__device__ inline void block_store1(float v, double* dst, float* sm,
                                    int lane, int wid, int tid) {
    v = wave_red_sum(v);
    if (lane == 0) sm[wid] = v;
    __syncthreads();
    if (tid == 0)
        *dst = (double)sm[0] + (double)sm[1] + (double)sm[2] + (double)sm[3];
}

__device__ inline float bce_term(float x, float y) {
    return fmaxf(x, 0.0f) - x * y + log1pf(__expf(-fabsf(x)));
}

// reduce one double array of length n with the whole block, fixed order
__device__ inline double block_red_d(const double* __restrict__ p, int n,
                                     double* sd) {
    const int tid = threadIdx.x;
    double s = 0.0;
    for (int i = tid; i < n; i += 256) s += p[i];
#pragma unroll
    for (int o = 32; o; o >>= 1) s += __shfl_down(s, o, 64);
    const int lane = tid & 63, wid = tid >> 6;
    __syncthreads();
    if (lane == 0) sd[wid] = s;
    __syncthreads();
    return sd[0] + sd[1] + sd[2] + sd[3];
}

__global__ __launch_bounds__(256) void tac2_loss_main(
    const float* __restrict__ mel_out, const float* __restrict__ mel_post,
    const float* __restrict__ gate_out, const float* __restrict__ align,
    const float* __restrict__ r_mu,    const float* __restrict__ r_lv,
    const float* __restrict__ spk_out, const float* __restrict__ aug_out,
    const float* __restrict__ mel_tgt, const float* __restrict__ gate_tgt,
    const float* __restrict__ spk_tgt, const float* __restrict__ aug_tgt,
    double* __restrict__ ws, unsigned int* __restrict__ done_cnt,
    const int* __restrict__ step_p, float* __restrict__ out)
{
    __shared__ float sm[4];
    const int bid = blockIdx.x, tid = threadIdx.x;
    const int lane = tid & 63, wid = tid >> 6;

    // role mapping: interleaved so each CU hosts a role mix
    const int quad = bid >> 2, rem = bid & 3;
    int role;          // 0=mel 1=align 2=gate 3=kl 4=ce
    int sub;
    if (rem == 0) { role = 0; sub = quad; }
    else          { role = 1; sub = quad * 3 + (rem - 1); }
    if (role == 1 && sub >= NB_AL) {
        const int t2 = sub - NB_AL;                            // 0..5
        if (t2 < NB_GATE) { role = 2; sub = t2; }
        else if (t2 == NB_GATE) { role = 3; sub = 0; }
        else { role = 4; sub = 0; }
    }

    if (role == 0) {
        // ---- mel: depth-2 pipelined grid-stride over 3 streams ----
        const float4* a = (const float4*)mel_out;
        const float4* p = (const float4*)mel_post;
        const float4* t = (const float4*)mel_tgt;
        const int STR = NB_MEL * 256;
        int i = sub * 256 + tid;
        float s = 0.f;
        float4 a0, p0, t0;
        if (i < NMEL4) { a0 = a[i]; p0 = p[i]; t0 = t[i]; }
        while (i < NMEL4) {
            const int j = i + STR;
            float4 a1, p1, t1;
            if (j < NMEL4) { a1 = a[j]; p1 = p[j]; t1 = t[j]; }  // prefetch
            float d;
            d = a0.x - t0.x; s = fmaf(d, d, s);
            d = a0.y - t0.y; s = fmaf(d, d, s);
            d = a0.z - t0.z; s = fmaf(d, d, s);
            d = a0.w - t0.w; s = fmaf(d, d, s);
            d = p0.x - t0.x; s = fmaf(d, d, s);
            d = p0.y - t0.y; s = fmaf(d, d, s);
            d = p0.z - t0.z; s = fmaf(d, d, s);
            d = p0.w - t0.w; s = fmaf(d, d, s);
            a0 = a1; p0 = p1; t0 = t1;
            i = j;
        }
        block_store1(s, ws + WS_MEL + sub, sm, lane, wid, tid);
    } else if (role == 1) {
        // ---- align: depth-2 pipelined grid-stride, 1 stream ----
        const float4* al = (const float4*)align;
        const int STR = NB_AL * 256;
        int i = sub * 256 + tid;
        float s = 0.f;
        float4 v0;
        if (i < NAL4) v0 = al[i];
        while (i < NAL4) {
            const int j = i + STR;
            float4 v1;
            if (j < NAL4) v1 = al[j];                             // prefetch
            const int e0 = i * 4;
            const float f[4] = {v0.x, v0.y, v0.z, v0.w};
#pragma unroll
            for (int jj = 0; jj < 4; ++jj) {
                const int e = e0 + jj;
                const int tt = e % 250;
                const int nn = (e / 250) % 1000;
                const float dd = nn * (1.0f / 1000.0f) - tt * (1.0f / 250.0f);
                const float w = 1.0f - __expf(-2.5f * dd * dd);
                s = fmaf(f[jj], w, s);
            }
            v0 = v1;
            i = j;
        }
        block_store1(s, ws + WS_AL + sub, sm, lane, wid, tid);
    } else if (role == 2) {
        // ---- gate BCE: 4 blocks, grid-stride over 16,000 float4 ----
        const float4* x4 = (const float4*)gate_out;
        const float4* y4 = (const float4*)gate_tgt;
        float s = 0.f;
        for (int i = sub * 256 + tid; i < NGATE / 4; i += NB_GATE * 256) {
            float4 x = x4[i], y = y4[i];
            s += bce_term(x.x, y.x) + bce_term(x.y, y.y) +
                 bce_term(x.z, y.z) + bce_term(x.w, y.w);
        }
        block_store1(s, ws + WS_GATE + sub, sm, lane, wid, tid);
    } else if (role == 3) {
        // ---- KL: sum(1 + lv - mu^2 - exp(lv)), 1024 elems ----
        float s = 0.f;
        for (int i = tid; i < NKL; i += 256) {
            const float mu = r_mu[i], lv = r_lv[i];
            s += 1.0f + lv - mu * mu - __expf(lv);
        }
        block_store1(s, ws + WS_KL, sm, lane, wid, tid);
    } else {
        // ---- CE: one wave per row; rows strided across 4 waves ----
        float spk_s = 0.f, aug_s = 0.f;
        for (int b = wid; b < 64; b += 4) {
            { // speaker: 128 cols -> 2 per lane
                const float* xo = spk_out + b * 128;
                const float* xt = spk_tgt + b * 128;
                const float x0 = xo[lane], x1 = xo[lane + 64];
                const float t0 = xt[lane], t1 = xt[lane + 64];
                float bv; int bi;
                if (t0 >= t1) { bv = t0; bi = lane; } else { bv = t1; bi = lane + 64; }
#pragma unroll
                for (int o = 32; o; o >>= 1) {
                    const float ov = __shfl_xor(bv, o, 64);
                    const int   oi = __shfl_xor(bi, o, 64);
                    if (ov > bv || (ov == bv && oi < bi)) { bv = ov; bi = oi; }
                }
                float m = fmaxf(x0, x1);
#pragma unroll
                for (int o = 32; o; o >>= 1) m = fmaxf(m, __shfl_xor(m, o, 64));
                float e = __expf(x0 - m) + __expf(x1 - m);
#pragma unroll
                for (int o = 32; o; o >>= 1) e += __shfl_xor(e, o, 64);
                if (lane == 0) spk_s += m + logf(e) - xo[bi];
            }
            { // aug: 10 cols
                const float* ao = aug_out + b * 10;
                const float* at = aug_tgt + b * 10;
                const float x  = (lane < 10) ? ao[lane] : -INFINITY;
                float bv = (lane < 10) ? at[lane] : -INFINITY;
                int   bi = (lane < 10) ? lane : (1 << 30);
#pragma unroll
                for (int o = 32; o; o >>= 1) {
                    const float ov = __shfl_xor(bv, o, 64);
                    const int   oi = __shfl_xor(bi, o, 64);
                    if (ov > bv || (ov == bv && oi < bi)) { bv = ov; bi = oi; }
                }
                float m = x;
#pragma unroll
                for (int o = 32; o; o >>= 1) m = fmaxf(m, __shfl_xor(m, o, 64));
                float e = (lane < 10) ? __expf(x - m) : 0.0f;
#pragma unroll
                for (int o = 32; o; o >>= 1) e += __shfl_xor(e, o, 64);
                if (lane == 0) aug_s += m + logf(e) - ao[bi];
            }
        }
        __shared__ double ce_sm[4][2];
        if (lane == 0) { ce_sm[wid][0] = (double)spk_s; ce_sm[wid][1] = (double)aug_s; }
        __syncthreads();
        if (tid == 0) {
            ws[WS_SPK] = ce_sm[0][0] + ce_sm[1][0] + ce_sm[2][0] + ce_sm[3][0];
            ws[WS_AUG] = ce_sm[0][1] + ce_sm[1][1] + ce_sm[2][1] + ce_sm[3][1];
        }
    }

    // ---- last-WG-done: fuse the final reduction into this dispatch ----
    __shared__ bool is_last;
    __threadfence();                      // release partial write (device scope)
    __syncthreads();                      // all waves of WG done before signal
    if (tid == 0) {
        const unsigned int prev = atomicAdd(done_cnt, 1u);
        is_last = (prev == (unsigned int)(NBLOCKS - 1));
    }
    __syncthreads();
    if (!is_last) return;

    __threadfence();                      // acquire: see all partials
    __shared__ double sd[4];
    const double s_mel  = block_red_d(ws + WS_MEL, NB_MEL, sd);
    const double s_al   = block_red_d(ws + WS_AL, NB_AL, sd);
    const double s_gate = block_red_d(ws + WS_GATE, NB_GATE, sd);

    if (tid == 0) {
        const double mel   = s_mel / (double)NMEL;   // (sum1+sum2)/NMEL
        const double gate  = s_gate / (double)NGATE;
        const double kl    = -0.5 * ws[WS_KL];
        const double alo   = fabs(s_al);
        const double spk   = ws[WS_SPK] / 64.0;
        const double aug   = ws[WS_AUG] / 64.0;
        const double step  = (double)step_p[0];
        const double w     = 1.0 / (1.0 + exp(-0.0025 * (step - 10000.0)));
        const double total = 10.0 * (mel + gate) + 0.01 * (kl * w) +
                             0.1 * spk + 0.1 * aug + 0.0005 * alo;
        out[0] = (float)total;
        out[1] = (float)(mel + gate);
        out[2] = (float)kl;
        out[3] = (float)w;
        out[4] = (float)spk;
        out[5] = (float)aug;
        out[6] = (float)alo;
    }
}

extern "C" void kernel_launch(void* const* d_in, const int* in_sizes, int n_in,
                              void* d_out, int out_size, void* d_ws, size_t ws_size,
                              hipStream_t stream) {
    const float* mel_out  = (const float*)d_in[0];
    const float* mel_post = (const float*)d_in[1];
    const float* gate_out = (const float*)d_in[2];
    const float* align    = (const float*)d_in[3];
    const float* r_mu     = (const float*)d_in[4];
    const float* r_lv     = (const float*)d_in[5];
    const float* spk_out  = (const float*)d_in[6];
    const float* aug_out  = (const float*)d_in[7];
    const float* mel_tgt  = (const float*)d_in[8];
    const float* gate_tgt = (const float*)d_in[9];
    const float* spk_tgt  = (const float*)d_in[10];
    const float* aug_tgt  = (const float*)d_in[11];
    const int*   step_p   = (const int*)d_in[12];

    double* ws = (double*)d_ws;
    unsigned int* done_cnt =
        (unsigned int*)((char*)d_ws + WS_CNT_OFF_BYTES);

    // zero ONLY the done-counter each call (graph-capture-safe, deterministic)
    hipMemsetAsync((void*)done_cnt, 0, sizeof(unsigned int), stream);

    tac2_loss_main<<<NBLOCKS, 256, 0, stream>>>(
        mel_out, mel_post, gate_out, align, r_mu, r_lv, spk_out, aug_out,
        mel_tgt, gate_tgt, spk_tgt, aug_tgt, ws, done_cnt, step_p,
        (float*)d_out);
}

// Round 8
// 60.261 us; speedup vs baseline: 4.2983x; 4.2983x over previous
//
#include <hip/hip_runtime.h>
#include <math.h>

// ---------------- problem constants (from setup_inputs) ----------------
// B=64, n_mel=80, T_mel=1000, N_dec=1000, T_enc=250, n_spk=128, n_aug=10, z=16
constexpr int NMEL  = 64 * 80 * 1000;   // 5,120,000 elems per mel tensor
constexpr int NAL   = 64 * 1000 * 250;  // 16,000,000 alignment elems
constexpr int NGATE = 64 * 1000;        // 64,000
constexpr int NKL   = 64 * 16;          // 1024
constexpr int NMEL4 = NMEL / 4;         // 1,280,000 float4
constexpr int NAL4  = NAL / 4;          // 4,000,000 float4

// ---------------- block-role partition: EXACTLY 8 WG/CU ----------------
// 2048 WGs total = 256 CU x 8 (32 waves/CU = HW max residency).
// Interleave roles so every CU gets ~2 mel + ~6 align:
//   bid % 4 == 0           -> mel   (512 WGs)
//   bid % 4 != 0, most     -> align (1530 WGs)
//   tail WGs               -> gate(4), KL(1), CE(1)
#define NB_MEL   512
#define NB_AL    1530
#define NB_GATE  4
#define NBLOCKS  2048      // 512 + 1530 + 4 + 1 + 1

// ws layout (doubles), one slot per block partial -> NO atomics:
#define WS_MEL   0         // 512 (s1+s2 combined)
#define WS_AL    512       // 1530
#define WS_GATE  2042      // 4
#define WS_KL    2046
#define WS_SPK   2047
#define WS_AUG   2048

__device__ inline float wave_red_sum(float v) {
#pragma unroll
    for (int o = 32; o; o >>= 1) v += __shfl_down(v, o, 64);
    return v;
}

__device__ inline void block_store1(float v, double* dst, float* sm,
                                    int lane, int wid, int tid) {
    v = wave_red_sum(v);
    if (lane == 0) sm[wid] = v;
    __syncthreads();
    if (tid == 0)
        *dst = (double)sm[0] + (double)sm[1] + (double)sm[2] + (double)sm[3];
}

__device__ inline float bce_term(float x, float y) {
    return fmaxf(x, 0.0f) - x * y + log1pf(__expf(-fabsf(x)));
}

__global__ __launch_bounds__(256) void tac2_loss_main(
    const float* __restrict__ mel_out, const float* __restrict__ mel_post,
    const float* __restrict__ gate_out, const float* __restrict__ align,
    const float* __restrict__ r_mu,    const float* __restrict__ r_lv,
    const float* __restrict__ spk_out, const float* __restrict__ aug_out,
    const float* __restrict__ mel_tgt, const float* __restrict__ gate_tgt,
    const float* __restrict__ spk_tgt, const float* __restrict__ aug_tgt,
    double* __restrict__ ws)
{
    __shared__ float sm[4];
    const int bid = blockIdx.x, tid = threadIdx.x;
    const int lane = tid & 63, wid = tid >> 6;

    // role mapping: interleaved so each CU hosts a role mix
    const int quad = bid >> 2, rem = bid & 3;
    int role;          // 0=mel 1=align 2=gate 3=kl 4=ce
    int sub;
    if (rem == 0) { role = 0; sub = quad; }                    // 512 mel
    else          { role = 1; sub = quad * 3 + (rem - 1); }    // 1536 slots
    if (role == 1 && sub >= NB_AL) {                           // last 6 slots
        const int t2 = sub - NB_AL;                            // 0..5
        if (t2 < NB_GATE) { role = 2; sub = t2; }
        else if (t2 == NB_GATE) { role = 3; sub = 0; }
        else { role = 4; sub = 0; }
    }

    if (role == 0) {
        // ---- mel: depth-2 pipelined grid-stride over 3 streams ----
        const float4* a = (const float4*)mel_out;
        const float4* p = (const float4*)mel_post;
        const float4* t = (const float4*)mel_tgt;
        const int STR = NB_MEL * 256;
        int i = sub * 256 + tid;
        float s = 0.f;
        float4 a0, p0, t0;
        if (i < NMEL4) { a0 = a[i]; p0 = p[i]; t0 = t[i]; }
        while (i < NMEL4) {
            const int j = i + STR;
            float4 a1, p1, t1;
            if (j < NMEL4) { a1 = a[j]; p1 = p[j]; t1 = t[j]; }  // prefetch
            float d;
            d = a0.x - t0.x; s = fmaf(d, d, s);
            d = a0.y - t0.y; s = fmaf(d, d, s);
            d = a0.z - t0.z; s = fmaf(d, d, s);
            d = a0.w - t0.w; s = fmaf(d, d, s);
            d = p0.x - t0.x; s = fmaf(d, d, s);
            d = p0.y - t0.y; s = fmaf(d, d, s);
            d = p0.z - t0.z; s = fmaf(d, d, s);
            d = p0.w - t0.w; s = fmaf(d, d, s);
            a0 = a1; p0 = p1; t0 = t1;
            i = j;
        }
        block_store1(s, ws + WS_MEL + sub, sm, lane, wid, tid);
    } else if (role == 1) {
        // ---- align: depth-2 pipelined grid-stride, 1 stream ----
        const float4* al = (const float4*)align;
        const int STR = NB_AL * 256;
        int i = sub * 256 + tid;
        float s = 0.f;
        float4 v0;
        if (i < NAL4) v0 = al[i];
        while (i < NAL4) {
            const int j = i + STR;
            float4 v1;
            if (j < NAL4) v1 = al[j];                             // prefetch
            const int e0 = i * 4;
            const float f[4] = {v0.x, v0.y, v0.z, v0.w};
#pragma unroll
            for (int jj = 0; jj < 4; ++jj) {
                const int e = e0 + jj;
                const int tt = e % 250;
                const int nn = (e / 250) % 1000;
                const float dd = nn * (1.0f / 1000.0f) - tt * (1.0f / 250.0f);
                const float w = 1.0f - __expf(-2.5f * dd * dd);
                s = fmaf(f[jj], w, s);
            }
            v0 = v1;
            i = j;
        }
        block_store1(s, ws + WS_AL + sub, sm, lane, wid, tid);
    } else if (role == 2) {
        // ---- gate BCE: 4 blocks, grid-stride over 16,000 float4 ----
        const float4* x4 = (const float4*)gate_out;
        const float4* y4 = (const float4*)gate_tgt;
        float s = 0.f;
        for (int i = sub * 256 + tid; i < NGATE / 4; i += NB_GATE * 256) {
            float4 x = x4[i], y = y4[i];
            s += bce_term(x.x, y.x) + bce_term(x.y, y.y) +
                 bce_term(x.z, y.z) + bce_term(x.w, y.w);
        }
        block_store1(s, ws + WS_GATE + sub, sm, lane, wid, tid);
    } else if (role == 3) {
        // ---- KL: sum(1 + lv - mu^2 - exp(lv)), 1024 elems ----
        float s = 0.f;
        for (int i = tid; i < NKL; i += 256) {
            const float mu = r_mu[i], lv = r_lv[i];
            s += 1.0f + lv - mu * mu - __expf(lv);
        }
        block_store1(s, ws + WS_KL, sm, lane, wid, tid);
    } else {
        // ---- CE: one wave per row; rows strided across 4 waves ----
        float spk_s = 0.f, aug_s = 0.f;
        for (int b = wid; b < 64; b += 4) {
            { // speaker: 128 cols -> 2 per lane
                const float* xo = spk_out + b * 128;
                const float* xt = spk_tgt + b * 128;
                const float x0 = xo[lane], x1 = xo[lane + 64];
                const float t0 = xt[lane], t1 = xt[lane + 64];
                float bv; int bi;
                if (t0 >= t1) { bv = t0; bi = lane; } else { bv = t1; bi = lane + 64; }
#pragma unroll
                for (int o = 32; o; o >>= 1) {
                    const float ov = __shfl_xor(bv, o, 64);
                    const int   oi = __shfl_xor(bi, o, 64);
                    if (ov > bv || (ov == bv && oi < bi)) { bv = ov; bi = oi; }
                }
                float m = fmaxf(x0, x1);
#pragma unroll
                for (int o = 32; o; o >>= 1) m = fmaxf(m, __shfl_xor(m, o, 64));
                float e = __expf(x0 - m) + __expf(x1 - m);
#pragma unroll
                for (int o = 32; o; o >>= 1) e += __shfl_xor(e, o, 64);
                if (lane == 0) spk_s += m + logf(e) - xo[bi];
            }
            { // aug: 10 cols
                const float* ao = aug_out + b * 10;
                const float* at = aug_tgt + b * 10;
                const float x  = (lane < 10) ? ao[lane] : -INFINITY;
                float bv = (lane < 10) ? at[lane] : -INFINITY;
                int   bi = (lane < 10) ? lane : (1 << 30);
#pragma unroll
                for (int o = 32; o; o >>= 1) {
                    const float ov = __shfl_xor(bv, o, 64);
                    const int   oi = __shfl_xor(bi, o, 64);
                    if (ov > bv || (ov == bv && oi < bi)) { bv = ov; bi = oi; }
                }
                float m = x;
#pragma unroll
                for (int o = 32; o; o >>= 1) m = fmaxf(m, __shfl_xor(m, o, 64));
                float e = (lane < 10) ? __expf(x - m) : 0.0f;
#pragma unroll
                for (int o = 32; o; o >>= 1) e += __shfl_xor(e, o, 64);
                if (lane == 0) aug_s += m + logf(e) - ao[bi];
            }
        }
        __shared__ double ce_sm[4][2];
        if (lane == 0) { ce_sm[wid][0] = (double)spk_s; ce_sm[wid][1] = (double)aug_s; }
        __syncthreads();
        if (tid == 0) {
            ws[WS_SPK] = ce_sm[0][0] + ce_sm[1][0] + ce_sm[2][0] + ce_sm[3][0];
            ws[WS_AUG] = ce_sm[0][1] + ce_sm[1][1] + ce_sm[2][1] + ce_sm[3][1];
        }
    }
}

// reduce one double array of length n with the whole block, fixed order
__device__ inline double block_red_d(const double* __restrict__ p, int n,
                                     double* sd) {
    const int tid = threadIdx.x;
    double s = 0.0;
    for (int i = tid; i < n; i += 256) s += p[i];
#pragma unroll
    for (int o = 32; o; o >>= 1) s += __shfl_down(s, o, 64);
    const int lane = tid & 63, wid = tid >> 6;
    __syncthreads();
    if (lane == 0) sd[wid] = s;
    __syncthreads();
    return sd[0] + sd[1] + sd[2] + sd[3];
}

__global__ __launch_bounds__(256) void tac2_loss_final(
    const double* __restrict__ ws, const int* __restrict__ step_p,
    float* __restrict__ out)
{
    __shared__ double sd[4];
    const double s_mel  = block_red_d(ws + WS_MEL, NB_MEL, sd);
    const double s_al   = block_red_d(ws + WS_AL, NB_AL, sd);
    const double s_gate = block_red_d(ws + WS_GATE, NB_GATE, sd);

    if (threadIdx.x == 0) {
        const double mel   = s_mel / (double)NMEL;   // (sum1+sum2)/NMEL
        const double gate  = s_gate / (double)NGATE;
        const double kl    = -0.5 * ws[WS_KL];
        const double alo   = fabs(s_al);
        const double spk   = ws[WS_SPK] / 64.0;
        const double aug   = ws[WS_AUG] / 64.0;
        const double step  = (double)step_p[0];
        const double w     = 1.0 / (1.0 + exp(-0.0025 * (step - 10000.0)));
        const double total = 10.0 * (mel + gate) + 0.01 * (kl * w) +
                             0.1 * spk + 0.1 * aug + 0.0005 * alo;
        out[0] = (float)total;
        out[1] = (float)(mel + gate);
        out[2] = (float)kl;
        out[3] = (float)w;
        out[4] = (float)spk;
        out[5] = (float)aug;
        out[6] = (float)alo;
    }
}

extern "C" void kernel_launch(void* const* d_in, const int* in_sizes, int n_in,
                              void* d_out, int out_size, void* d_ws, size_t ws_size,
                              hipStream_t stream) {
    const float* mel_out  = (const float*)d_in[0];
    const float* mel_post = (const float*)d_in[1];
    const float* gate_out = (const float*)d_in[2];
    const float* align    = (const float*)d_in[3];
    const float* r_mu     = (const float*)d_in[4];
    const float* r_lv     = (const float*)d_in[5];
    const float* spk_out  = (const float*)d_in[6];
    const float* aug_out  = (const float*)d_in[7];
    const float* mel_tgt  = (const float*)d_in[8];
    const float* gate_tgt = (const float*)d_in[9];
    const float* spk_tgt  = (const float*)d_in[10];
    const float* aug_tgt  = (const float*)d_in[11];
    const int*   step_p   = (const int*)d_in[12];

    double* ws = (double*)d_ws;

    tac2_loss_main<<<NBLOCKS, 256, 0, stream>>>(
        mel_out, mel_post, gate_out, align, r_mu, r_lv, spk_out, aug_out,
        mel_tgt, gate_tgt, spk_tgt, aug_tgt, ws);

    tac2_loss_final<<<1, 256, 0, stream>>>(ws, step_p, (float*)d_out);
}